// Round 1
// baseline (1818.096 us; speedup 1.0000x reference)
//
#include <hip/hip_runtime.h>
#include <math.h>

#define BB 8
#define SS 1024
#define DD 768
#define HH 12
#define DEP 64

// ---------------------------------------------------------------------------
// QKV projection: Y = X @ W + b, written in head-split layout (B,H,S,DEP).
// 128x128 tile per 256-thread block, BK=8, 8x8 micro-tile per thread.
// grid.z in {0,1,2} selects (q,wq,bq)->qh, (k,wk,bk)->kh, (v,wv,bv)->vh.
// ---------------------------------------------------------------------------
__global__ __launch_bounds__(256) void qkv_proj_kernel(
    const float* __restrict__ v_in, const float* __restrict__ k_in,
    const float* __restrict__ q_in,
    const float* __restrict__ wq, const float* __restrict__ bq,
    const float* __restrict__ wk, const float* __restrict__ bk,
    const float* __restrict__ wv, const float* __restrict__ bv,
    float* __restrict__ qh, float* __restrict__ kh, float* __restrict__ vh)
{
    const int z = blockIdx.z;
    const float* X    = (z == 0) ? q_in : (z == 1) ? k_in : v_in;
    const float* W    = (z == 0) ? wq   : (z == 1) ? wk   : wv;
    const float* bias = (z == 0) ? bq   : (z == 1) ? bk   : bv;
    float*       Y    = (z == 0) ? qh   : (z == 1) ? kh   : vh;

    const int m0 = blockIdx.y * 128;
    const int n0 = blockIdx.x * 128;
    const int tid = threadIdx.x;
    const int ty = tid >> 4, tx = tid & 15;

    __shared__ float As[8][132];   // A transposed: As[kk][m]
    __shared__ float Bs[8][132];   // Bs[kk][n]

    float acc[8][8];
#pragma unroll
    for (int j = 0; j < 8; ++j)
#pragma unroll
        for (int i = 0; i < 8; ++i) acc[j][i] = 0.f;

    const int arow = tid >> 1, akq = (tid & 1) * 4;
    const int brow = tid >> 5, bnq = (tid & 31) * 4;

    for (int k0 = 0; k0 < DD; k0 += 8) {
        const float4 av  = *(const float4*)(X + (size_t)(m0 + arow) * DD + k0 + akq);
        const float4 bv4 = *(const float4*)(W + (size_t)(k0 + brow) * DD + n0 + bnq);
        __syncthreads();
        As[akq + 0][arow] = av.x;
        As[akq + 1][arow] = av.y;
        As[akq + 2][arow] = av.z;
        As[akq + 3][arow] = av.w;
        *(float4*)&Bs[brow][bnq] = bv4;
        __syncthreads();
#pragma unroll
        for (int kk = 0; kk < 8; ++kk) {
            float a[8], bb[8];
            *(float4*)&a[0]  = *(const float4*)&As[kk][ty * 8];
            *(float4*)&a[4]  = *(const float4*)&As[kk][ty * 8 + 4];
            *(float4*)&bb[0] = *(const float4*)&Bs[kk][tx * 8];
            *(float4*)&bb[4] = *(const float4*)&Bs[kk][tx * 8 + 4];
#pragma unroll
            for (int j = 0; j < 8; ++j)
#pragma unroll
                for (int i = 0; i < 8; ++i)
                    acc[j][i] = fmaf(a[j], bb[i], acc[j][i]);
        }
    }

#pragma unroll
    for (int j = 0; j < 8; ++j) {
        const int m  = m0 + ty * 8 + j;
        const int bi = m >> 10, si = m & 1023;
#pragma unroll
        for (int i = 0; i < 8; ++i) {
            const int n  = n0 + tx * 8 + i;
            const int hh = n >> 6, dp = n & 63;
            Y[(((size_t)bi * HH + hh) * SS + si) * DEP + dp] = acc[j][i] + bias[n];
        }
    }
}

// ---------------------------------------------------------------------------
// Out projection: out = concat @ wo + bo (plain row-major output).
// ---------------------------------------------------------------------------
__global__ __launch_bounds__(256) void out_proj_kernel(
    const float* __restrict__ Xc, const float* __restrict__ W,
    const float* __restrict__ bias, float* __restrict__ Y)
{
    const int m0 = blockIdx.y * 128;
    const int n0 = blockIdx.x * 128;
    const int tid = threadIdx.x;
    const int ty = tid >> 4, tx = tid & 15;

    __shared__ float As[8][132];
    __shared__ float Bs[8][132];

    float acc[8][8];
#pragma unroll
    for (int j = 0; j < 8; ++j)
#pragma unroll
        for (int i = 0; i < 8; ++i) acc[j][i] = 0.f;

    const int arow = tid >> 1, akq = (tid & 1) * 4;
    const int brow = tid >> 5, bnq = (tid & 31) * 4;

    for (int k0 = 0; k0 < DD; k0 += 8) {
        const float4 av  = *(const float4*)(Xc + (size_t)(m0 + arow) * DD + k0 + akq);
        const float4 bv4 = *(const float4*)(W + (size_t)(k0 + brow) * DD + n0 + bnq);
        __syncthreads();
        As[akq + 0][arow] = av.x;
        As[akq + 1][arow] = av.y;
        As[akq + 2][arow] = av.z;
        As[akq + 3][arow] = av.w;
        *(float4*)&Bs[brow][bnq] = bv4;
        __syncthreads();
#pragma unroll
        for (int kk = 0; kk < 8; ++kk) {
            float a[8], bb[8];
            *(float4*)&a[0]  = *(const float4*)&As[kk][ty * 8];
            *(float4*)&a[4]  = *(const float4*)&As[kk][ty * 8 + 4];
            *(float4*)&bb[0] = *(const float4*)&Bs[kk][tx * 8];
            *(float4*)&bb[4] = *(const float4*)&Bs[kk][tx * 8 + 4];
#pragma unroll
            for (int j = 0; j < 8; ++j)
#pragma unroll
                for (int i = 0; i < 8; ++i)
                    acc[j][i] = fmaf(a[j], bb[i], acc[j][i]);
        }
    }

#pragma unroll
    for (int j = 0; j < 8; ++j) {
        const int m = m0 + ty * 8 + j;
#pragma unroll
        for (int i = 0; i < 8; ++i) {
            const int n = n0 + tx * 8 + i;
            Y[(size_t)m * DD + n] = acc[j][i] + bias[n];
        }
    }
}

// ---------------------------------------------------------------------------
// Fused attention: per block = one (b, h, 64-row q-block).
// Sweep A: online softmax stats (row max m_, row sum l_) — nothing stored.
// Sweep B: recompute scores, write normalized attn ONCE, accumulate P @ V.
// Thread mapping for 64x64 score tiles: ty=tid/16 rows {ty+16j},
// tx=tid%15 cols {tx+16i} — strided 4x4 micro-tile, conflict-free LDS reads.
// ---------------------------------------------------------------------------
__global__ __launch_bounds__(256) void attn_softmax_pv_kernel(
    const float* __restrict__ qh, const float* __restrict__ kh,
    const float* __restrict__ vh, const float* __restrict__ mask,
    const float* __restrict__ adjoin,
    float* __restrict__ attn_out, float* __restrict__ concat)
{
    const int bid = blockIdx.x;
    const int rb  = bid & 15;
    const int h   = (bid >> 4) % HH;
    const int b   = bid / (16 * HH);
    const int r0  = rb * 64;

    const float* qb  = qh + ((size_t)(b * HH + h)) * SS * DEP;
    const float* kb  = kh + ((size_t)(b * HH + h)) * SS * DEP;
    const float* vb  = vh + ((size_t)(b * HH + h)) * SS * DEP;
    const float* adj = adjoin + (size_t)b * SS * SS;
    const float* mk  = mask + (size_t)b * SS;
    float* attn = attn_out + ((size_t)(b * HH + h)) * SS * SS;

    __shared__ float qT[64][68];   // qT[kk][r]
    __shared__ float kT[64][68];   // kT[kk][c]
    __shared__ float vS[64][68];   // vS[c][dep]
    __shared__ float pS[64][68];   // pS[r][c]

    const int tid = threadIdx.x;
    const int ty = tid >> 4, tx = tid & 15;

    // load Q block (64 rows x 64 depth), transposed into qT[kk][r]
#pragma unroll
    for (int rr = 0; rr < 4; ++rr) {
        const int row = rr * 16 + ty;
        const int kk0 = tx * 4;
        const float4 qv = *(const float4*)(qb + (size_t)(r0 + row) * DEP + kk0);
        qT[kk0 + 0][row] = qv.x; qT[kk0 + 1][row] = qv.y;
        qT[kk0 + 2][row] = qv.z; qT[kk0 + 3][row] = qv.w;
    }

    float m_[4], l_[4];
#pragma unroll
    for (int j = 0; j < 4; ++j) { m_[j] = -INFINITY; l_[j] = 0.f; }

    // ---------------- Sweep A: online max + sum ----------------
    for (int t = 0; t < 16; ++t) {
        const int c0 = t * 64;
        float4 kv[4];
#pragma unroll
        for (int rr = 0; rr < 4; ++rr)
            kv[rr] = *(const float4*)(kb + (size_t)(c0 + rr * 16 + ty) * DEP + tx * 4);
        __syncthreads();
#pragma unroll
        for (int rr = 0; rr < 4; ++rr) {
            const int row = rr * 16 + ty, kk0 = tx * 4;
            kT[kk0 + 0][row] = kv[rr].x; kT[kk0 + 1][row] = kv[rr].y;
            kT[kk0 + 2][row] = kv[rr].z; kT[kk0 + 3][row] = kv[rr].w;
        }
        __syncthreads();

        float sc[4][4];
#pragma unroll
        for (int j = 0; j < 4; ++j)
#pragma unroll
            for (int i = 0; i < 4; ++i) sc[j][i] = 0.f;
#pragma unroll 8
        for (int kk = 0; kk < 64; ++kk) {
            float a[4], bb[4];
#pragma unroll
            for (int j = 0; j < 4; ++j) a[j] = qT[kk][ty + 16 * j];
#pragma unroll
            for (int i = 0; i < 4; ++i) bb[i] = kT[kk][tx + 16 * i];
#pragma unroll
            for (int j = 0; j < 4; ++j)
#pragma unroll
                for (int i = 0; i < 4; ++i)
                    sc[j][i] = fmaf(a[j], bb[i], sc[j][i]);
        }
#pragma unroll
        for (int j = 0; j < 4; ++j) {
            const int r = r0 + ty + 16 * j;
#pragma unroll
            for (int i = 0; i < 4; ++i) {
                const int c = c0 + tx + 16 * i;
                sc[j][i] = sc[j][i] * 0.125f - 1e9f * mk[c] + adj[(size_t)r * SS + c];
            }
        }
#pragma unroll
        for (int j = 0; j < 4; ++j) {
            float tmax = fmaxf(fmaxf(sc[j][0], sc[j][1]), fmaxf(sc[j][2], sc[j][3]));
#pragma unroll
            for (int off = 1; off < 16; off <<= 1)
                tmax = fmaxf(tmax, __shfl_xor(tmax, off));
            const float mn = fmaxf(m_[j], tmax);
            float ps = __expf(sc[j][0] - mn) + __expf(sc[j][1] - mn)
                     + __expf(sc[j][2] - mn) + __expf(sc[j][3] - mn);
#pragma unroll
            for (int off = 1; off < 16; off <<= 1)
                ps += __shfl_xor(ps, off);
            l_[j] = l_[j] * __expf(m_[j] - mn) + ps;
            m_[j] = mn;
        }
    }

    float invl[4];
#pragma unroll
    for (int j = 0; j < 4; ++j) invl[j] = 1.0f / l_[j];

    float oacc[4][4];
#pragma unroll
    for (int j = 0; j < 4; ++j)
#pragma unroll
        for (int i = 0; i < 4; ++i) oacc[j][i] = 0.f;

    // ---------------- Sweep B: write attn + accumulate P @ V ----------------
    for (int t = 0; t < 16; ++t) {
        const int c0 = t * 64;
        float4 kv[4], vv4[4];
#pragma unroll
        for (int rr = 0; rr < 4; ++rr) {
            kv[rr]  = *(const float4*)(kb + (size_t)(c0 + rr * 16 + ty) * DEP + tx * 4);
            vv4[rr] = *(const float4*)(vb + (size_t)(c0 + rr * 16 + ty) * DEP + tx * 4);
        }
        __syncthreads();
#pragma unroll
        for (int rr = 0; rr < 4; ++rr) {
            const int row = rr * 16 + ty, kk0 = tx * 4;
            kT[kk0 + 0][row] = kv[rr].x; kT[kk0 + 1][row] = kv[rr].y;
            kT[kk0 + 2][row] = kv[rr].z; kT[kk0 + 3][row] = kv[rr].w;
            *(float4*)&vS[row][kk0] = vv4[rr];
        }
        __syncthreads();

        float sc[4][4];
#pragma unroll
        for (int j = 0; j < 4; ++j)
#pragma unroll
            for (int i = 0; i < 4; ++i) sc[j][i] = 0.f;
#pragma unroll 8
        for (int kk = 0; kk < 64; ++kk) {
            float a[4], bb[4];
#pragma unroll
            for (int j = 0; j < 4; ++j) a[j] = qT[kk][ty + 16 * j];
#pragma unroll
            for (int i = 0; i < 4; ++i) bb[i] = kT[kk][tx + 16 * i];
#pragma unroll
            for (int j = 0; j < 4; ++j)
#pragma unroll
                for (int i = 0; i < 4; ++i)
                    sc[j][i] = fmaf(a[j], bb[i], sc[j][i]);
        }
#pragma unroll
        for (int j = 0; j < 4; ++j) {
            const int r = r0 + ty + 16 * j;
#pragma unroll
            for (int i = 0; i < 4; ++i) {
                const int c = c0 + tx + 16 * i;
                const float lg = sc[j][i] * 0.125f - 1e9f * mk[c] + adj[(size_t)r * SS + c];
                const float p  = __expf(lg - m_[j]) * invl[j];
                attn[(size_t)r * SS + c] = p;
                pS[ty + 16 * j][tx + 16 * i] = p;
            }
        }
        __syncthreads();
        // oacc[r][dep] += sum_c pS[r][c] * vS[c][dep]
#pragma unroll 8
        for (int c = 0; c < 64; ++c) {
            float pv[4], vvv[4];
#pragma unroll
            for (int j = 0; j < 4; ++j) pv[j] = pS[ty + 16 * j][c];
#pragma unroll
            for (int i = 0; i < 4; ++i) vvv[i] = vS[c][tx + 16 * i];
#pragma unroll
            for (int j = 0; j < 4; ++j)
#pragma unroll
                for (int i = 0; i < 4; ++i)
                    oacc[j][i] = fmaf(pv[j], vvv[i], oacc[j][i]);
        }
    }

    // write concat (B,S,D) with d = h*64 + dep
#pragma unroll
    for (int j = 0; j < 4; ++j) {
        const int s = r0 + ty + 16 * j;
#pragma unroll
        for (int i = 0; i < 4; ++i) {
            const int dp = tx + 16 * i;
            concat[((size_t)b * SS + s) * DD + h * DEP + dp] = oacc[j][i];
        }
    }
}

// ---------------------------------------------------------------------------
extern "C" void kernel_launch(void* const* d_in, const int* in_sizes, int n_in,
                              void* d_out, int out_size, void* d_ws, size_t ws_size,
                              hipStream_t stream)
{
    (void)in_sizes; (void)n_in; (void)out_size; (void)ws_size;

    const float* v      = (const float*)d_in[0];
    const float* k      = (const float*)d_in[1];
    const float* q      = (const float*)d_in[2];
    const float* mask   = (const float*)d_in[3];
    const float* adjoin = (const float*)d_in[4];
    const float* wq     = (const float*)d_in[5];
    const float* bq     = (const float*)d_in[6];
    const float* wk     = (const float*)d_in[7];
    const float* bk     = (const float*)d_in[8];
    const float* wv     = (const float*)d_in[9];
    const float* bv     = (const float*)d_in[10];
    const float* wo     = (const float*)d_in[11];
    const float* bo     = (const float*)d_in[12];

    float* out  = (float*)d_out;                         // (B,S,D)
    float* attn = out + (size_t)BB * SS * DD;            // (B,H,S,S)

    const size_t N1 = (size_t)BB * SS * DD;              // 6,291,456 floats
    float* ws     = (float*)d_ws;
    float* qh     = ws;                                  // (B,H,S,DEP)
    float* kh     = ws + N1;
    float* vh     = ws + 2 * N1;
    float* concat = ws + 3 * N1;                         // (B,S,D)

    qkv_proj_kernel<<<dim3(DD / 128, (BB * SS) / 128, 3), 256, 0, stream>>>(
        v, k, q, wq, bq, wk, bk, wv, bv, qh, kh, vh);

    attn_softmax_pv_kernel<<<dim3(16 * HH * BB), 256, 0, stream>>>(
        qh, kh, vh, mask, adjoin, attn, concat);

    out_proj_kernel<<<dim3(DD / 128, (BB * SS) / 128, 1), 256, 0, stream>>>(
        concat, wo, bo, out);
}

// Round 2
// 913.146 us; speedup vs baseline: 1.9910x; 1.9910x over previous
//
#include <hip/hip_runtime.h>
#include <math.h>

#define BB 8
#define SS 1024
#define DD 768
#define HH 12
#define DEP 64

typedef __attribute__((ext_vector_type(8))) short short8;
typedef __attribute__((ext_vector_type(4))) float floatx4;

// round-to-nearest-even fp32 -> bf16 (bit pattern in ushort)
static __device__ __forceinline__ unsigned short f2bf(float x) {
    union { float f; unsigned u; } v; v.f = x;
    unsigned r = v.u + 0x7fffu + ((v.u >> 16) & 1u);
    return (unsigned short)(r >> 16);
}

// ---------------------------------------------------------------------------
// fp32 -> bf16 conversion for q,k,v inputs (each N1=6291456 elems, /4 exact)
// ---------------------------------------------------------------------------
__global__ __launch_bounds__(256) void conv_inputs_kernel(
    const float* __restrict__ q, const float* __restrict__ k,
    const float* __restrict__ v,
    unsigned short* __restrict__ qb, unsigned short* __restrict__ kb,
    unsigned short* __restrict__ vb)
{
    const int y = blockIdx.y;
    const float* src = (y == 0) ? q : (y == 1) ? k : v;
    unsigned short* dst = (y == 0) ? qb : (y == 1) ? kb : vb;
    const size_t i = ((size_t)blockIdx.x * 256 + threadIdx.x) * 4;
    const float4 f = *(const float4*)(src + i);
    ushort4 o;
    o.x = f2bf(f.x); o.y = f2bf(f.y); o.z = f2bf(f.z); o.w = f2bf(f.w);
    *(ushort4*)(dst + i) = o;
}

// ---------------------------------------------------------------------------
// weights: fp32 768x768 [k][n] -> bf16 transposed [n][k] (LDS 32x32 tiles)
// ---------------------------------------------------------------------------
__global__ __launch_bounds__(256) void conv_wT_kernel(
    const float* __restrict__ wq, const float* __restrict__ wk,
    const float* __restrict__ wv, const float* __restrict__ wo,
    unsigned short* __restrict__ wqT, unsigned short* __restrict__ wkT,
    unsigned short* __restrict__ wvT, unsigned short* __restrict__ woT)
{
    const int z = blockIdx.z;
    const float* W = (z == 0) ? wq : (z == 1) ? wk : (z == 2) ? wv : wo;
    unsigned short* WT = (z == 0) ? wqT : (z == 1) ? wkT : (z == 2) ? wvT : woT;
    __shared__ float tile[32][33];
    const int tx = threadIdx.x & 31, ty = threadIdx.x >> 5;
    const int k0 = blockIdx.y * 32, n0 = blockIdx.x * 32;
#pragma unroll
    for (int r = 0; r < 4; ++r)
        tile[ty + r * 8][tx] = W[(size_t)(k0 + ty + r * 8) * DD + n0 + tx];
    __syncthreads();
#pragma unroll
    for (int r = 0; r < 4; ++r)
        WT[(size_t)(n0 + ty + r * 8) * DD + k0 + tx] = f2bf(tile[tx][ty + r * 8]);
}

// ---------------------------------------------------------------------------
// bf16 MFMA GEMM 128x128, BK=64, 4 waves (2x2, 64x64 each).
// A: (M x 768) bf16 row-major; BT: (768 x 768) bf16 [n][k].
// QKV variant writes bf16 head-split (B,H,S,DEP); out variant writes fp32.
// ---------------------------------------------------------------------------
__global__ __launch_bounds__(256) void qkv_gemm_kernel(
    const unsigned short* __restrict__ qb, const unsigned short* __restrict__ kb,
    const unsigned short* __restrict__ vb,
    const unsigned short* __restrict__ wqT, const unsigned short* __restrict__ wkT,
    const unsigned short* __restrict__ wvT,
    const float* __restrict__ bq, const float* __restrict__ bk,
    const float* __restrict__ bv,
    unsigned short* __restrict__ qh, unsigned short* __restrict__ kh,
    unsigned short* __restrict__ vh)
{
    const int z = blockIdx.z;
    const unsigned short* A  = (z == 0) ? qb  : (z == 1) ? kb  : vb;
    const unsigned short* BT = (z == 0) ? wqT : (z == 1) ? wkT : wvT;
    const float* bias        = (z == 0) ? bq  : (z == 1) ? bk  : bv;
    unsigned short* Y        = (z == 0) ? qh  : (z == 1) ? kh  : vh;

    const int m0 = blockIdx.y * 128, n0 = blockIdx.x * 128;
    const int tid = threadIdx.x;
    const int wave = tid >> 6, lane = tid & 63;
    const int quad = lane >> 4, l16 = lane & 15;
    const int wm = (wave & 1) * 64, wn = (wave >> 1) * 64;

    __shared__ unsigned short aS[128][72];
    __shared__ unsigned short bS[128][72];

    floatx4 acc[4][4];
#pragma unroll
    for (int i = 0; i < 4; ++i)
#pragma unroll
        for (int j = 0; j < 4; ++j) acc[i][j] = (floatx4){0.f, 0.f, 0.f, 0.f};

    for (int k0 = 0; k0 < DD; k0 += 64) {
        __syncthreads();
#pragma unroll
        for (int it = 0; it < 4; ++it) {
            const int f = it * 256 + tid;
            const int row = f >> 3, c8 = (f & 7) * 8;
            *(float4*)&aS[row][c8] = *(const float4*)&A[(size_t)(m0 + row) * DD + k0 + c8];
            *(float4*)&bS[row][c8] = *(const float4*)&BT[(size_t)(n0 + row) * DD + k0 + c8];
        }
        __syncthreads();
        short8 a[2][4], b[2][4];
#pragma unroll
        for (int kc = 0; kc < 2; ++kc)
#pragma unroll
            for (int t = 0; t < 4; ++t) {
                a[kc][t] = *(const short8*)&aS[wm + t * 16 + l16][kc * 32 + quad * 8];
                b[kc][t] = *(const short8*)&bS[wn + t * 16 + l16][kc * 32 + quad * 8];
            }
#pragma unroll
        for (int kc = 0; kc < 2; ++kc)
#pragma unroll
            for (int tm = 0; tm < 4; ++tm)
#pragma unroll
                for (int tn = 0; tn < 4; ++tn)
                    acc[tm][tn] = __builtin_amdgcn_mfma_f32_16x16x32_bf16(
                        a[kc][tm], b[kc][tn], acc[tm][tn], 0, 0, 0);
    }

#pragma unroll
    for (int tm = 0; tm < 4; ++tm)
#pragma unroll
        for (int tn = 0; tn < 4; ++tn)
#pragma unroll
            for (int r = 0; r < 4; ++r) {
                const int row = m0 + wm + tm * 16 + quad * 4 + r;
                const int col = n0 + wn + tn * 16 + l16;
                const float val = acc[tm][tn][r] + bias[col];
                const int bi = row >> 10, s = row & 1023;
                const int hh = col >> 6, dp = col & 63;
                Y[(((size_t)bi * HH + hh) * SS + s) * DEP + dp] = f2bf(val);
            }
}

__global__ __launch_bounds__(256) void out_gemm_kernel(
    const unsigned short* __restrict__ A, const unsigned short* __restrict__ BT,
    const float* __restrict__ bias, float* __restrict__ Y)
{
    const int m0 = blockIdx.y * 128, n0 = blockIdx.x * 128;
    const int tid = threadIdx.x;
    const int wave = tid >> 6, lane = tid & 63;
    const int quad = lane >> 4, l16 = lane & 15;
    const int wm = (wave & 1) * 64, wn = (wave >> 1) * 64;

    __shared__ unsigned short aS[128][72];
    __shared__ unsigned short bS[128][72];

    floatx4 acc[4][4];
#pragma unroll
    for (int i = 0; i < 4; ++i)
#pragma unroll
        for (int j = 0; j < 4; ++j) acc[i][j] = (floatx4){0.f, 0.f, 0.f, 0.f};

    for (int k0 = 0; k0 < DD; k0 += 64) {
        __syncthreads();
#pragma unroll
        for (int it = 0; it < 4; ++it) {
            const int f = it * 256 + tid;
            const int row = f >> 3, c8 = (f & 7) * 8;
            *(float4*)&aS[row][c8] = *(const float4*)&A[(size_t)(m0 + row) * DD + k0 + c8];
            *(float4*)&bS[row][c8] = *(const float4*)&BT[(size_t)(n0 + row) * DD + k0 + c8];
        }
        __syncthreads();
        short8 a[2][4], b[2][4];
#pragma unroll
        for (int kc = 0; kc < 2; ++kc)
#pragma unroll
            for (int t = 0; t < 4; ++t) {
                a[kc][t] = *(const short8*)&aS[wm + t * 16 + l16][kc * 32 + quad * 8];
                b[kc][t] = *(const short8*)&bS[wn + t * 16 + l16][kc * 32 + quad * 8];
            }
#pragma unroll
        for (int kc = 0; kc < 2; ++kc)
#pragma unroll
            for (int tm = 0; tm < 4; ++tm)
#pragma unroll
                for (int tn = 0; tn < 4; ++tn)
                    acc[tm][tn] = __builtin_amdgcn_mfma_f32_16x16x32_bf16(
                        a[kc][tm], b[kc][tn], acc[tm][tn], 0, 0, 0);
    }

#pragma unroll
    for (int tm = 0; tm < 4; ++tm)
#pragma unroll
        for (int tn = 0; tn < 4; ++tn)
#pragma unroll
            for (int r = 0; r < 4; ++r) {
                const int row = m0 + wm + tm * 16 + quad * 4 + r;
                const int col = n0 + wn + tn * 16 + l16;
                Y[(size_t)row * DD + col] = acc[tm][tn][r] + bias[col];
            }
}

// ---------------------------------------------------------------------------
// Fused attention, bf16 MFMA. Block = (b,h,64 q-rows); wave w owns rows
// w*16..w*16+15. Sweep A: QK^T via MFMA + online max/sum. Sweep B: recompute
// scores, write fp32 attn, P->bf16 LDS, P@V via MFMA.
// MFMA 16x16x32_bf16 layouts (HW-verified per guide):
//   A[m=lane&15][k=quad*8+j], B[k=quad*8+j][n=lane&15],
//   C/D: col=lane&15, row=quad*4+reg.
// ---------------------------------------------------------------------------
__global__ __launch_bounds__(256) void attn_kernel(
    const unsigned short* __restrict__ qh, const unsigned short* __restrict__ kh,
    const unsigned short* __restrict__ vh, const float* __restrict__ mask,
    const float* __restrict__ adjoin, float* __restrict__ attn_out,
    unsigned short* __restrict__ concat)
{
    const int bid = blockIdx.x;
    const int rb = bid & 15;
    const int h  = (bid >> 4) % HH;
    const int b  = bid / (16 * HH);
    const int r0 = rb * 64;

    const unsigned short* qbp = qh + ((size_t)(b * HH + h)) * SS * DEP;
    const unsigned short* kbp = kh + ((size_t)(b * HH + h)) * SS * DEP;
    const unsigned short* vbp = vh + ((size_t)(b * HH + h)) * SS * DEP;
    const float* adj = adjoin + (size_t)b * SS * SS;
    const float* mk  = mask + (size_t)b * SS;
    float* attn = attn_out + ((size_t)(b * HH + h)) * SS * SS;

    __shared__ unsigned short qS[64][72];
    __shared__ unsigned short kS[64][72];
    __shared__ unsigned short vT[64][72];   // vT[dep][c]
    __shared__ unsigned short pS[64][72];   // pS[r][c] bf16

    const int tid = threadIdx.x;
    const int wave = tid >> 6, lane = tid & 63;
    const int quad = lane >> 4, l16 = lane & 15;

    // stage Q once (64 rows x 64 deps bf16)
#pragma unroll
    for (int it = 0; it < 2; ++it) {
        const int f = it * 256 + tid;
        const int row = f >> 3, c8 = (f & 7) * 8;
        *(float4*)&qS[row][c8] = *(const float4*)&qbp[(size_t)(r0 + row) * DEP + c8];
    }
    __syncthreads();
    short8 aq0 = *(const short8*)&qS[wave * 16 + l16][quad * 8];
    short8 aq1 = *(const short8*)&qS[wave * 16 + l16][32 + quad * 8];

    float m_[4], l_[4];
#pragma unroll
    for (int r = 0; r < 4; ++r) { m_[r] = -INFINITY; l_[r] = 0.f; }

    // ---------------- Sweep A ----------------
    for (int t = 0; t < 16; ++t) {
        __syncthreads();
#pragma unroll
        for (int it = 0; it < 2; ++it) {
            const int f = it * 256 + tid;
            const int row = f >> 3, c8 = (f & 7) * 8;
            *(float4*)&kS[row][c8] = *(const float4*)&kbp[(size_t)(t * 64 + row) * DEP + c8];
        }
        __syncthreads();

        floatx4 sc[4];
#pragma unroll
        for (int tn = 0; tn < 4; ++tn) {
            const short8 b0 = *(const short8*)&kS[tn * 16 + l16][quad * 8];
            const short8 b1 = *(const short8*)&kS[tn * 16 + l16][32 + quad * 8];
            floatx4 z = (floatx4){0.f, 0.f, 0.f, 0.f};
            z = __builtin_amdgcn_mfma_f32_16x16x32_bf16(aq0, b0, z, 0, 0, 0);
            z = __builtin_amdgcn_mfma_f32_16x16x32_bf16(aq1, b1, z, 0, 0, 0);
            sc[tn] = z;
        }

        float lg[4][4];
#pragma unroll
        for (int tn = 0; tn < 4; ++tn) {
            const int c = t * 64 + tn * 16 + l16;
            const float mv = -1e9f * mk[c];
#pragma unroll
            for (int r = 0; r < 4; ++r) {
                const int gr = r0 + wave * 16 + quad * 4 + r;
                lg[tn][r] = sc[tn][r] * 0.125f + mv + adj[(size_t)gr * SS + c];
            }
        }
#pragma unroll
        for (int r = 0; r < 4; ++r) {
            float tmax = fmaxf(fmaxf(lg[0][r], lg[1][r]), fmaxf(lg[2][r], lg[3][r]));
            tmax = fmaxf(tmax, __shfl_xor(tmax, 1));
            tmax = fmaxf(tmax, __shfl_xor(tmax, 2));
            tmax = fmaxf(tmax, __shfl_xor(tmax, 4));
            tmax = fmaxf(tmax, __shfl_xor(tmax, 8));
            const float mn = fmaxf(m_[r], tmax);
            float ps = __expf(lg[0][r] - mn) + __expf(lg[1][r] - mn)
                     + __expf(lg[2][r] - mn) + __expf(lg[3][r] - mn);
            ps += __shfl_xor(ps, 1);
            ps += __shfl_xor(ps, 2);
            ps += __shfl_xor(ps, 4);
            ps += __shfl_xor(ps, 8);
            l_[r] = l_[r] * __expf(m_[r] - mn) + ps;
            m_[r] = mn;
        }
    }

    float invl[4];
#pragma unroll
    for (int r = 0; r < 4; ++r) invl[r] = 1.0f / l_[r];

    floatx4 oacc[4];
#pragma unroll
    for (int tn = 0; tn < 4; ++tn) oacc[tn] = (floatx4){0.f, 0.f, 0.f, 0.f};

    // ---------------- Sweep B ----------------
    for (int t = 0; t < 16; ++t) {
        __syncthreads();
#pragma unroll
        for (int it = 0; it < 2; ++it) {
            const int f = it * 256 + tid;
            const int row = f >> 3, c8 = (f & 7) * 8;
            *(float4*)&kS[row][c8] = *(const float4*)&kbp[(size_t)(t * 64 + row) * DEP + c8];
            union { float4 f4; unsigned short u[8]; } vv;
            vv.f4 = *(const float4*)&vbp[(size_t)(t * 64 + row) * DEP + c8];
#pragma unroll
            for (int j = 0; j < 8; ++j) vT[c8 + j][row] = vv.u[j];
        }
        __syncthreads();

        floatx4 sc[4];
#pragma unroll
        for (int tn = 0; tn < 4; ++tn) {
            const short8 b0 = *(const short8*)&kS[tn * 16 + l16][quad * 8];
            const short8 b1 = *(const short8*)&kS[tn * 16 + l16][32 + quad * 8];
            floatx4 z = (floatx4){0.f, 0.f, 0.f, 0.f};
            z = __builtin_amdgcn_mfma_f32_16x16x32_bf16(aq0, b0, z, 0, 0, 0);
            z = __builtin_amdgcn_mfma_f32_16x16x32_bf16(aq1, b1, z, 0, 0, 0);
            sc[tn] = z;
        }
#pragma unroll
        for (int tn = 0; tn < 4; ++tn) {
            const int c = t * 64 + tn * 16 + l16;
            const float mv = -1e9f * mk[c];
#pragma unroll
            for (int r = 0; r < 4; ++r) {
                const int lr = wave * 16 + quad * 4 + r;
                const int gr = r0 + lr;
                const float lgv = sc[tn][r] * 0.125f + mv + adj[(size_t)gr * SS + c];
                const float p = __expf(lgv - m_[r]) * invl[r];
                attn[(size_t)gr * SS + c] = p;
                pS[lr][tn * 16 + l16] = f2bf(p);
            }
        }
        __syncthreads();

        const short8 ap0 = *(const short8*)&pS[wave * 16 + l16][quad * 8];
        const short8 ap1 = *(const short8*)&pS[wave * 16 + l16][32 + quad * 8];
#pragma unroll
        for (int tn = 0; tn < 4; ++tn) {
            const short8 bv0 = *(const short8*)&vT[tn * 16 + l16][quad * 8];
            const short8 bv1 = *(const short8*)&vT[tn * 16 + l16][32 + quad * 8];
            oacc[tn] = __builtin_amdgcn_mfma_f32_16x16x32_bf16(ap0, bv0, oacc[tn], 0, 0, 0);
            oacc[tn] = __builtin_amdgcn_mfma_f32_16x16x32_bf16(ap1, bv1, oacc[tn], 0, 0, 0);
        }
    }

#pragma unroll
    for (int tn = 0; tn < 4; ++tn)
#pragma unroll
        for (int r = 0; r < 4; ++r) {
            const int s = r0 + wave * 16 + quad * 4 + r;
            const int dp = tn * 16 + l16;
            concat[((size_t)b * SS + s) * DD + h * DEP + dp] = f2bf(oacc[tn][r]);
        }
}

// ---------------------------------------------------------------------------
extern "C" void kernel_launch(void* const* d_in, const int* in_sizes, int n_in,
                              void* d_out, int out_size, void* d_ws, size_t ws_size,
                              hipStream_t stream)
{
    (void)in_sizes; (void)n_in; (void)out_size; (void)ws_size;

    const float* v      = (const float*)d_in[0];
    const float* k      = (const float*)d_in[1];
    const float* q      = (const float*)d_in[2];
    const float* mask   = (const float*)d_in[3];
    const float* adjoin = (const float*)d_in[4];
    const float* wq     = (const float*)d_in[5];
    const float* bq     = (const float*)d_in[6];
    const float* wk     = (const float*)d_in[7];
    const float* bk     = (const float*)d_in[8];
    const float* wv     = (const float*)d_in[9];
    const float* bv     = (const float*)d_in[10];
    const float* wo     = (const float*)d_in[11];
    const float* bo     = (const float*)d_in[12];

    float* out  = (float*)d_out;                 // (B,S,D) fp32
    float* attn = out + (size_t)BB * SS * DD;    // (B,H,S,S) fp32

    const size_t N1 = (size_t)BB * SS * DD;      // 6,291,456
    const size_t NW = (size_t)DD * DD;           // 589,824
    unsigned short* ws = (unsigned short*)d_ws;
    unsigned short* qb      = ws;                // bf16 (B*S, D)
    unsigned short* kb      = ws + N1;
    unsigned short* vb      = ws + 2 * N1;
    unsigned short* qhb     = ws + 3 * N1;       // bf16 (B,H,S,DEP)
    unsigned short* khb     = ws + 4 * N1;
    unsigned short* vhb     = ws + 5 * N1;
    unsigned short* concatb = ws + 6 * N1;       // bf16 (B,S,D)
    unsigned short* wqT     = ws + 7 * N1;       // bf16 (768,768) [n][k]
    unsigned short* wkT     = wqT + NW;
    unsigned short* wvT     = wkT + NW;
    unsigned short* woT     = wvT + NW;

    conv_inputs_kernel<<<dim3((unsigned)(N1 / 4 / 256), 3), 256, 0, stream>>>(
        q, k, v, qb, kb, vb);
    conv_wT_kernel<<<dim3(24, 24, 4), 256, 0, stream>>>(
        wq, wk, wv, wo, wqT, wkT, wvT, woT);

    qkv_gemm_kernel<<<dim3(DD / 128, (BB * SS) / 128, 3), 256, 0, stream>>>(
        qb, kb, vb, wqT, wkT, wvT, bq, bk, bv, qhb, khb, vhb);

    attn_kernel<<<dim3(16 * HH * BB), 256, 0, stream>>>(
        qhb, khb, vhb, mask, adjoin, attn, concatb);

    out_gemm_kernel<<<dim3(DD / 128, (BB * SS) / 128), 256, 0, stream>>>(
        concatb, woT, bo, out);
}